// Round 4
// baseline (2571.619 us; speedup 1.0000x reference)
//
#include <hip/hip_runtime.h>
#include <math.h>

#define E_EDGES 8192
#define D_FEAT 2048
#define K2 4096   // 2*D
#define H_DIM 128
#define N_NODES 100000
#define SIM_TH 0.7f
#define NSLOTS (2 * E_EDGES)   // 16384 compact slots
#define UFB 16                 // edges per speculative batch (32 walker lanes)

// ---------------------------------------------------------------------------
// Kernel 1: cosine similarity per edge. One wave (64 lanes) per edge.
// ---------------------------------------------------------------------------
__global__ __launch_bounds__(256) void sim_kernel(const float* __restrict__ xf,
                                                  const float* __restrict__ yf,
                                                  float* __restrict__ sim) {
    int gid  = blockIdx.x * blockDim.x + threadIdx.x;
    int wave = gid >> 6;
    int lane = threadIdx.x & 63;
    if (wave >= E_EDGES) return;
    const float4* xp = (const float4*)(xf + (size_t)wave * D_FEAT);
    const float4* yp = (const float4*)(yf + (size_t)wave * D_FEAT);
    float dot = 0.f, xx = 0.f, yy = 0.f;
#pragma unroll
    for (int j = 0; j < 8; ++j) {
        float4 a = xp[lane + j * 64];
        float4 b = yp[lane + j * 64];
        dot += a.x * b.x + a.y * b.y + a.z * b.z + a.w * b.w;
        xx  += a.x * a.x + a.y * a.y + a.z * a.z + a.w * a.w;
        yy  += b.x * b.x + b.y * b.y + b.z * b.z + b.w * b.w;
    }
#pragma unroll
    for (int off = 32; off; off >>= 1) {
        dot += __shfl_xor(dot, off);
        xx  += __shfl_xor(xx, off);
        yy  += __shfl_xor(yy, off);
    }
    if (lane == 0) {
        float nx = fmaxf(sqrtf(xx), 1e-8f);
        float ny = fmaxf(sqrtf(yy), 1e-8f);
        sim[wave] = dot / (nx * ny);
    }
}

// ---------------------------------------------------------------------------
// Kernel 2: init fo (=INT_MAX), orig (=-1), and zero w output.
// ---------------------------------------------------------------------------
__global__ void initmap_kernel(int* __restrict__ fo, int* __restrict__ orig,
                               float* __restrict__ wout) {
    int i = blockIdx.x * blockDim.x + threadIdx.x;
    if (i < N_NODES) fo[i] = 0x7FFFFFFF;
    if (i < NSLOTS)  orig[i] = -1;
    if (i < E_EDGES) wout[i] = 0.f;
}

// ---------------------------------------------------------------------------
// Kernel 3: claim compact slot = first occurrence index in x0,y0,x1,y1,...
// ---------------------------------------------------------------------------
__global__ void claim_kernel(const int* __restrict__ x_idx, const int* __restrict__ y_idx,
                             int* __restrict__ fo) {
    int i = blockIdx.x * blockDim.x + threadIdx.x;
    if (i >= NSLOTS) return;
    int e = i >> 1;
    int v = (i & 1) ? y_idx[e] : x_idx[e];
    atomicMin(&fo[v], i);
}

// ---------------------------------------------------------------------------
// Kernel 4: orig[slot] = node for claimed slots.
// ---------------------------------------------------------------------------
__global__ void orig_kernel(const int* __restrict__ x_idx, const int* __restrict__ y_idx,
                            const int* __restrict__ fo, int* __restrict__ orig) {
    int i = blockIdx.x * blockDim.x + threadIdx.x;
    if (i >= NSLOTS) return;
    int e = i >> 1;
    int v = (i & 1) ? y_idx[e] : x_idx[e];
    if (fo[v] == i) orig[i] = v;
}

// ---------------------------------------------------------------------------
// Kernel 5: order-preserving compaction of masked edges into records
//           rec = {cx, cy, eidx, (w filled later by gate)}.
// ---------------------------------------------------------------------------
__global__ __launch_bounds__(256) void maskscan_kernel(
        const int* __restrict__ x_idx, const int* __restrict__ y_idx,
        const int* __restrict__ fo, const float* __restrict__ sim,
        int4* __restrict__ rec, int* __restrict__ nmask) {
    __shared__ int partial[256];
    int t = threadIdx.x;
    int cnt = 0;
    for (int j = 0; j < 32; ++j) {
        int e = t * 32 + j;
        cnt += (sim[e] >= SIM_TH) ? 1 : 0;
    }
    partial[t] = cnt;
    __syncthreads();
    for (int off = 1; off < 256; off <<= 1) {
        int mine  = partial[t];
        int other = (t >= off) ? partial[t - off] : 0;
        __syncthreads();
        partial[t] = mine + other;
        __syncthreads();
    }
    int pos = partial[t] - cnt;
    if (t == 255) *nmask = partial[255];
    for (int j = 0; j < 32; ++j) {
        int e = t * 32 + j;
        if (sim[e] >= SIM_TH) {
            int4 r;
            r.x = fo[x_idx[e]];
            r.y = fo[y_idx[e]];
            r.z = e;
            r.w = 0;
            rec[pos++] = r;
        }
    }
}

// ---------------------------------------------------------------------------
// Kernel 6: gate MLP over MASKED edges only (gathered rows).
// ---------------------------------------------------------------------------
#define BM 32
#define BK 32
#define SWZ(r, c) ((c) ^ ((((r) >> 2) & 7) << 2))

__global__ __launch_bounds__(256) void gate_kernel(
        const float* __restrict__ xf, const float* __restrict__ yf,
        const float* __restrict__ W1, const float* __restrict__ b1,
        const float* __restrict__ W2, const float* __restrict__ b2,
        int4* __restrict__ rec, const int* __restrict__ nmask,
        float* __restrict__ wout) {
    __shared__ float As[BM][BK];
    __shared__ float Bs[H_DIM][BK];
    __shared__ float red[BM][33];
    __shared__ int   elds[BM];

    int n  = *nmask;
    int b0 = blockIdx.x * BM;
    if (b0 >= n) return;

    int t  = threadIdx.x;
    if (t < BM) {
        int idx = b0 + t;
        elds[t] = (idx < n) ? rec[idx].z : rec[b0].z;
    }
    __syncthreads();

    int te = t >> 5;
    int tn = t & 31;
    int n0 = tn * 4;

    float acc[4][4] = {};

    for (int k0 = 0; k0 < K2; k0 += BK) {
        const float* src = (k0 < D_FEAT) ? xf : yf;
        int kk0 = (k0 < D_FEAT) ? k0 : (k0 - D_FEAT);
        {
            int row = t >> 3;
            int c   = (t & 7) * 4;
            float4 v = *(const float4*)(src + (size_t)elds[row] * D_FEAT + kk0 + c);
            *(float4*)(&As[row][SWZ(row, c)]) = v;
        }
#pragma unroll
        for (int r = 0; r < 4; ++r) {
            int nn = (t >> 3) + r * 32;
            int c  = (t & 7) * 4;
            float4 v = *(const float4*)(W1 + (size_t)nn * K2 + k0 + c);
            *(float4*)(&Bs[nn][SWZ(nn, c)]) = v;
        }
        __syncthreads();
        int swzA = (te & 7) << 2;
        int swzB = (tn & 7) << 2;
#pragma unroll
        for (int kk = 0; kk < BK; kk += 4) {
            float4 av[4], bv[4];
#pragma unroll
            for (int i = 0; i < 4; ++i)
                av[i] = *(const float4*)(&As[te * 4 + i][kk ^ swzA]);
#pragma unroll
            for (int j = 0; j < 4; ++j)
                bv[j] = *(const float4*)(&Bs[n0 + j][kk ^ swzB]);
#pragma unroll
            for (int i = 0; i < 4; ++i)
#pragma unroll
                for (int j = 0; j < 4; ++j)
                    acc[i][j] += av[i].x * bv[j].x + av[i].y * bv[j].y +
                                 av[i].z * bv[j].z + av[i].w * bv[j].w;
        }
        __syncthreads();
    }

    float b1v[4], w2v[4];
#pragma unroll
    for (int j = 0; j < 4; ++j) { b1v[j] = b1[n0 + j]; w2v[j] = W2[n0 + j]; }
#pragma unroll
    for (int i = 0; i < 4; ++i) {
        float p = 0.f;
#pragma unroll
        for (int j = 0; j < 4; ++j) {
            float h = fmaxf(acc[i][j] + b1v[j], 0.f);
            p += h * w2v[j];
        }
        red[te * 4 + i][tn] = p;
    }
    __syncthreads();
    if (t < BM && b0 + t < n) {
        float s = 0.f;
#pragma unroll
        for (int c = 0; c < 32; ++c) s += red[t][c];
        float logit = s + b2[0];
        float attn  = 1.f / (1.f + expf(-logit));
        wout[elds[t]] = attn;
        ((int*)&rec[b0 + t])[3] = __float_as_int(attn);
    }
}

// ---------------------------------------------------------------------------
// Exact serial processing of one edge (used for conflict redo / deep fallback).
// Runs on a single lane. nd = {parent, rank-bits} records, mk = epoch markers.
// ---------------------------------------------------------------------------
__device__ __noinline__ void serial_edge(int2* nd, unsigned char* mk,
                                         const int* ri, int eidx, int epoch) {
    int x = ri[eidx * 4 + 0], y = ri[eidx * 4 + 1];
    float w = __int_as_float(ri[eidx * 4 + 3]);
    int p, j;
    int rx = x;
    while ((p = nd[rx].x) != rx) rx = p;
    j = x;
    while (j != rx) { int nj = nd[j].x; nd[j].x = rx; mk[j] = (unsigned char)epoch; j = nj; }
    int ry = y;
    while ((p = nd[ry].x) != ry) ry = p;
    j = y;
    while (j != ry) { int nj = nd[j].x; nd[j].x = ry; mk[j] = (unsigned char)epoch; j = nj; }
    if (rx != ry) {
        float a = __int_as_float(nd[rx].y), b = __int_as_float(nd[ry].y);
        bool bx = a > b;
        int big = bx ? rx : ry, small = bx ? ry : rx;
        nd[small].x = big;
        nd[big].y = __float_as_int(bx ? (a + b * w) : (b + a * w));
        mk[small] = (unsigned char)epoch;
        mk[big]   = (unsigned char)epoch;
    }
}

// ---------------------------------------------------------------------------
// Kernel 7: batched speculative union-find in LDS.
//   Wave 0: per batch of 16 edges, 32 lanes walk all find-chains in parallel
//   (read-only), then edges are applied in order with epoch-marker conflict
//   detection; any conflict (incl. false positives) -> exact serial redo.
// ---------------------------------------------------------------------------
__global__ __launch_bounds__(256) void uf_kernel(
        const int4* __restrict__ rec, const int* __restrict__ nmask,
        const int* __restrict__ orig, const float* __restrict__ rin,
        int* __restrict__ gpar, float* __restrict__ grank) {
    extern __shared__ char smem[];
    int2* nd = (int2*)smem;                                  // 128 KB {parent, rank}
    unsigned char* mk = (unsigned char*)(smem + 131072);     // 16 KB epoch markers

    int t = threadIdx.x;
    for (int c = t; c < NSLOTS; c += 256) {
        int o = orig[c];
        float r = (o >= 0) ? rin[o] : 1.0f;
        nd[c] = make_int2(c, __float_as_int(r));             // parent == arange
    }
    __syncthreads();

    if (t < 64) {
        const int lane = t;
        const int owner_e = lane >> 1;
        const bool isOwner = lane < 2 * UFB;
        const int* ri = (const int*)rec;
        const int n = *nmask;

        for (int base = 0, b = 0; base < n; base += UFB, ++b) {
            const int nb = (n - base < UFB) ? (n - base) : UFB;
            const int epoch = b & 255;
            const bool valid = isOwner && (owner_e < nb);

            int myS = 0; float myW = 0.f;
            if (valid) {
                int e4 = (base + owner_e) * 4;
                myS = ri[e4 + (lane & 1)];
                myW = __int_as_float(ri[e4 + 3]);
            }

            // ---- WALK (read-only): all 32 chains in lockstep ----
            int cur = myS;
            int root = cur; float rrk = 1.0f;
            int p0 = myS, p1 = myS, p2 = myS, p3 = myS;
            int cnt = 0; bool done = false, deep = false;
#pragma unroll
            for (int k = 0; k < 5; ++k) {
                int2 pr = nd[cur];
                if (!done) {
                    if (pr.x == cur) { root = cur; rrk = __int_as_float(pr.y); done = true; }
                    else if (k < 4) {
                        if (k == 0) p0 = cur; else if (k == 1) p1 = cur;
                        else if (k == 2) p2 = cur; else p3 = cur;
                        cnt = k + 1; cur = pr.x;
                    } else { deep = true; done = true; }
                }
                if (k < 4 && __ballot(valid && !done) == 0ULL) break;
            }

            if (__ballot(valid && deep) != 0ULL) {
                // rare: some chain deeper than 4 -> exact serial whole batch
                if (lane == 0)
                    for (int e2 = 0; e2 < nb; ++e2) serial_edge(nd, mk, ri, base + e2, epoch);
                continue;
            }

            // ---- APPLY in order with conflict checks ----
            int c0 = 0, c1 = 0, c2 = 0, c3 = 0, c4 = 0;
#pragma unroll
            for (int e = 0; e < UFB; ++e) {
                if (e >= nb) break;
                const bool own = isOwner && (owner_e == e);
                bool conflict = false;
                if (e > 0) {
                    bool hit = own && (c0 == epoch || c1 == epoch || c2 == epoch ||
                                       c3 == epoch || c4 == epoch);
                    conflict = (__ballot(hit) != 0ULL);
                }
                if (conflict) {
                    if (lane == 0) serial_edge(nd, mk, ri, base + e, epoch);
                } else {
                    int rootO = __shfl_xor(root, 1);
                    float rkO = __shfl_xor(rrk, 1);
                    if (own) {
                        // path compression (exact reference write-set)
                        if (cnt > 0) { nd[p0].x = root; mk[p0] = (unsigned char)epoch; }
                        if (cnt > 1) { nd[p1].x = root; mk[p1] = (unsigned char)epoch; }
                        if (cnt > 2) { nd[p2].x = root; mk[p2] = (unsigned char)epoch; }
                        if (cnt > 3) { nd[p3].x = root; mk[p3] = (unsigned char)epoch; }
                        const bool evenL = (lane & 1) == 0;
                        int rx   = evenL ? root : rootO;
                        int ry   = evenL ? rootO : root;
                        float rax = evenL ? rrk : rkO;
                        float ray = evenL ? rkO : rrk;
                        if (rx != ry && evenL) {
                            bool bx = rax > ray;
                            int big = bx ? rx : ry, small = bx ? ry : rx;
                            float nr = bx ? (rax + ray * myW) : (ray + rax * myW);
                            nd[small].x = big;
                            nd[big].y = __float_as_int(nr);
                            mk[small] = (unsigned char)epoch;
                            mk[big]   = (unsigned char)epoch;
                        }
                    }
                }
                // issue next edge's conflict-check reads (latency hidden)
                if (e + 1 < UFB) {
                    bool own2 = isOwner && (owner_e == e + 1);
                    if (own2) {
                        c0 = mk[p0]; c1 = mk[p1]; c2 = mk[p2]; c3 = mk[p3]; c4 = mk[root];
                    }
                }
            }
        }
    }
    __syncthreads();
    for (int c = t; c < NSLOTS; c += 256) {
        int2 v = nd[c];
        gpar[c] = v.x;
        grank[c] = __int_as_float(v.y);
    }
}

// ---------------------------------------------------------------------------
// Kernel 8: base output = copy inputs.
// ---------------------------------------------------------------------------
__global__ void base_kernel(const int* __restrict__ pin, const float* __restrict__ rin,
                            float* __restrict__ pout, float* __restrict__ rout) {
    int i = blockIdx.x * blockDim.x + threadIdx.x;
    if (i < N_NODES) { pout[i] = (float)pin[i]; rout[i] = rin[i]; }
}

// ---------------------------------------------------------------------------
// Kernel 9: scatter compact results back to original ids.
// ---------------------------------------------------------------------------
__global__ void scatter_kernel(const int* __restrict__ orig, const int* __restrict__ gpar,
                               const float* __restrict__ grank,
                               float* __restrict__ pout, float* __restrict__ rout) {
    int c = blockIdx.x * blockDim.x + threadIdx.x;
    if (c >= NSLOTS) return;
    int o = orig[c];
    if (o >= 0) {
        pout[o] = (float)orig[gpar[c]];
        rout[o] = grank[c];
    }
}

// ---------------------------------------------------------------------------
extern "C" void kernel_launch(void* const* d_in, const int* in_sizes, int n_in,
                              void* d_out, int out_size, void* d_ws, size_t ws_size,
                              hipStream_t stream) {
    const int*   x_idx = (const int*)d_in[0];
    const int*   y_idx = (const int*)d_in[1];
    const float* xf    = (const float*)d_in[2];
    const float* yf    = (const float*)d_in[3];
    const float* W1    = (const float*)d_in[4];
    const float* b1    = (const float*)d_in[5];
    const float* W2    = (const float*)d_in[6];
    const float* b2    = (const float*)d_in[7];
    const int*   pin   = (const int*)d_in[8];
    const float* rin   = (const float*)d_in[9];

    float* out   = (float*)d_out;
    float* w_out = out;                        // [E]
    float* pout  = out + E_EDGES;              // [N]
    float* rout  = out + E_EDGES + N_NODES;    // [N]

    char* ws = (char*)d_ws;
    float* sim_ws = (float*)(ws + 0);          //  32768 B
    int*   fo     = (int*)  (ws + 32768);      // 400000 B
    int*   orig   = (int*)  (ws + 432768);     //  65536 B
    int4*  rec    = (int4*) (ws + 498304);     // (E+4)*16 = 131136 B
    int*   nmask  = (int*)  (ws + 629440);     //     64 B
    int*   gpar   = (int*)  (ws + 629504);     //  65536 B
    float* grank  = (float*)(ws + 695040);     //  65536 B -> total 760576 B

    // 1) cosine sim
    sim_kernel<<<(E_EDGES * 64) / 256, 256, 0, stream>>>(xf, yf, sim_ws);
    // 2) compact-id mapping + zero w
    int g = (N_NODES + 255) / 256;
    initmap_kernel<<<g, 256, 0, stream>>>(fo, orig, w_out);
    claim_kernel<<<NSLOTS / 256, 256, 0, stream>>>(x_idx, y_idx, fo);
    orig_kernel<<<NSLOTS / 256, 256, 0, stream>>>(x_idx, y_idx, fo, orig);
    // 3) masked-edge compaction (records)
    maskscan_kernel<<<1, 256, 0, stream>>>(x_idx, y_idx, fo, sim_ws, rec, nmask);
    // 4) gate MLP over masked edges only
    gate_kernel<<<E_EDGES / BM, 256, 0, stream>>>(xf, yf, W1, b1, W2, b2, rec, nmask, w_out);
    // 5) batched speculative union-find in LDS (128KB records + 16KB markers)
    uf_kernel<<<1, 256, 147456, stream>>>(rec, nmask, orig, rin, gpar, grank);
    // 6) emit outputs
    base_kernel<<<g, 256, 0, stream>>>(pin, rin, pout, rout);
    scatter_kernel<<<NSLOTS / 256, 256, 0, stream>>>(orig, gpar, grank, pout, rout);
}

// Round 5
// 2145.787 us; speedup vs baseline: 1.1985x; 1.1985x over previous
//
#include <hip/hip_runtime.h>
#include <math.h>

#define E_EDGES 8192
#define D_FEAT 2048
#define K2 4096   // 2*D
#define H_DIM 128
#define N_NODES 100000
#define SIM_TH 0.7f
#define NSLOTS (2 * E_EDGES)   // 16384 compact slots

// ---------------------------------------------------------------------------
// Kernel 1: cosine similarity per edge. One wave (64 lanes) per edge.
// ---------------------------------------------------------------------------
__global__ __launch_bounds__(256) void sim_kernel(const float* __restrict__ xf,
                                                  const float* __restrict__ yf,
                                                  float* __restrict__ sim) {
    int gid  = blockIdx.x * blockDim.x + threadIdx.x;
    int wave = gid >> 6;
    int lane = threadIdx.x & 63;
    if (wave >= E_EDGES) return;
    const float4* xp = (const float4*)(xf + (size_t)wave * D_FEAT);
    const float4* yp = (const float4*)(yf + (size_t)wave * D_FEAT);
    float dot = 0.f, xx = 0.f, yy = 0.f;
#pragma unroll
    for (int j = 0; j < 8; ++j) {
        float4 a = xp[lane + j * 64];
        float4 b = yp[lane + j * 64];
        dot += a.x * b.x + a.y * b.y + a.z * b.z + a.w * b.w;
        xx  += a.x * a.x + a.y * a.y + a.z * a.z + a.w * a.w;
        yy  += b.x * b.x + b.y * b.y + b.z * b.z + b.w * b.w;
    }
#pragma unroll
    for (int off = 32; off; off >>= 1) {
        dot += __shfl_xor(dot, off);
        xx  += __shfl_xor(xx, off);
        yy  += __shfl_xor(yy, off);
    }
    if (lane == 0) {
        float nx = fmaxf(sqrtf(xx), 1e-8f);
        float ny = fmaxf(sqrtf(yy), 1e-8f);
        sim[wave] = dot / (nx * ny);
    }
}

// ---------------------------------------------------------------------------
// Kernel 2: init fo (=INT_MAX), orig (=-1), and zero w output.
// ---------------------------------------------------------------------------
__global__ void initmap_kernel(int* __restrict__ fo, int* __restrict__ orig,
                               float* __restrict__ wout) {
    int i = blockIdx.x * blockDim.x + threadIdx.x;
    if (i < N_NODES) fo[i] = 0x7FFFFFFF;
    if (i < NSLOTS)  orig[i] = -1;
    if (i < E_EDGES) wout[i] = 0.f;
}

// ---------------------------------------------------------------------------
// Kernel 3: claim compact slot = first occurrence index in x0,y0,x1,y1,...
// ---------------------------------------------------------------------------
__global__ void claim_kernel(const int* __restrict__ x_idx, const int* __restrict__ y_idx,
                             int* __restrict__ fo) {
    int i = blockIdx.x * blockDim.x + threadIdx.x;
    if (i >= NSLOTS) return;
    int e = i >> 1;
    int v = (i & 1) ? y_idx[e] : x_idx[e];
    atomicMin(&fo[v], i);
}

// ---------------------------------------------------------------------------
// Kernel 4: orig[slot] = node for claimed slots.
// ---------------------------------------------------------------------------
__global__ void orig_kernel(const int* __restrict__ x_idx, const int* __restrict__ y_idx,
                            const int* __restrict__ fo, int* __restrict__ orig) {
    int i = blockIdx.x * blockDim.x + threadIdx.x;
    if (i >= NSLOTS) return;
    int e = i >> 1;
    int v = (i & 1) ? y_idx[e] : x_idx[e];
    if (fo[v] == i) orig[i] = v;
}

// ---------------------------------------------------------------------------
// Kernel 5: order-preserving compaction of masked edges into records
//           rec = {cx, cy, eidx, (w filled later by gate)} + 4 zero pads.
// ---------------------------------------------------------------------------
__global__ __launch_bounds__(256) void maskscan_kernel(
        const int* __restrict__ x_idx, const int* __restrict__ y_idx,
        const int* __restrict__ fo, const float* __restrict__ sim,
        int4* __restrict__ rec, int* __restrict__ nmask) {
    __shared__ int partial[256];
    int t = threadIdx.x;
    int cnt = 0;
    for (int j = 0; j < 32; ++j) {
        int e = t * 32 + j;
        cnt += (sim[e] >= SIM_TH) ? 1 : 0;
    }
    partial[t] = cnt;
    __syncthreads();
    for (int off = 1; off < 256; off <<= 1) {
        int mine  = partial[t];
        int other = (t >= off) ? partial[t - off] : 0;
        __syncthreads();
        partial[t] = mine + other;
        __syncthreads();
    }
    int pos = partial[t] - cnt;
    if (t == 255) {
        int nn = partial[255];
        *nmask = nn;
        for (int j = 0; j < 4; ++j) rec[nn + j] = make_int4(0, 0, 0, 0);
    }
    for (int j = 0; j < 32; ++j) {
        int e = t * 32 + j;
        if (sim[e] >= SIM_TH) {
            int4 r;
            r.x = fo[x_idx[e]];
            r.y = fo[y_idx[e]];
            r.z = e;
            r.w = 0;
            rec[pos++] = r;
        }
    }
}

// ---------------------------------------------------------------------------
// Kernel 6: gate MLP over MASKED edges only (gathered rows).
// ---------------------------------------------------------------------------
#define BM 32
#define BK 32
#define SWZ(r, c) ((c) ^ ((((r) >> 2) & 7) << 2))

__global__ __launch_bounds__(256) void gate_kernel(
        const float* __restrict__ xf, const float* __restrict__ yf,
        const float* __restrict__ W1, const float* __restrict__ b1,
        const float* __restrict__ W2, const float* __restrict__ b2,
        int4* __restrict__ rec, const int* __restrict__ nmask,
        float* __restrict__ wout) {
    __shared__ float As[BM][BK];
    __shared__ float Bs[H_DIM][BK];
    __shared__ float red[BM][33];
    __shared__ int   elds[BM];

    int n  = *nmask;
    int b0 = blockIdx.x * BM;
    if (b0 >= n) return;

    int t  = threadIdx.x;
    if (t < BM) {
        int idx = b0 + t;
        elds[t] = (idx < n) ? rec[idx].z : rec[b0].z;
    }
    __syncthreads();

    int te = t >> 5;
    int tn = t & 31;
    int n0 = tn * 4;

    float acc[4][4] = {};

    for (int k0 = 0; k0 < K2; k0 += BK) {
        const float* src = (k0 < D_FEAT) ? xf : yf;
        int kk0 = (k0 < D_FEAT) ? k0 : (k0 - D_FEAT);
        {
            int row = t >> 3;
            int c   = (t & 7) * 4;
            float4 v = *(const float4*)(src + (size_t)elds[row] * D_FEAT + kk0 + c);
            *(float4*)(&As[row][SWZ(row, c)]) = v;
        }
#pragma unroll
        for (int r = 0; r < 4; ++r) {
            int nn = (t >> 3) + r * 32;
            int c  = (t & 7) * 4;
            float4 v = *(const float4*)(W1 + (size_t)nn * K2 + k0 + c);
            *(float4*)(&Bs[nn][SWZ(nn, c)]) = v;
        }
        __syncthreads();
        int swzA = (te & 7) << 2;
        int swzB = (tn & 7) << 2;
#pragma unroll
        for (int kk = 0; kk < BK; kk += 4) {
            float4 av[4], bv[4];
#pragma unroll
            for (int i = 0; i < 4; ++i)
                av[i] = *(const float4*)(&As[te * 4 + i][kk ^ swzA]);
#pragma unroll
            for (int j = 0; j < 4; ++j)
                bv[j] = *(const float4*)(&Bs[n0 + j][kk ^ swzB]);
#pragma unroll
            for (int i = 0; i < 4; ++i)
#pragma unroll
                for (int j = 0; j < 4; ++j)
                    acc[i][j] += av[i].x * bv[j].x + av[i].y * bv[j].y +
                                 av[i].z * bv[j].z + av[i].w * bv[j].w;
        }
        __syncthreads();
    }

    float b1v[4], w2v[4];
#pragma unroll
    for (int j = 0; j < 4; ++j) { b1v[j] = b1[n0 + j]; w2v[j] = W2[n0 + j]; }
#pragma unroll
    for (int i = 0; i < 4; ++i) {
        float p = 0.f;
#pragma unroll
        for (int j = 0; j < 4; ++j) {
            float h = fmaxf(acc[i][j] + b1v[j], 0.f);
            p += h * w2v[j];
        }
        red[te * 4 + i][tn] = p;
    }
    __syncthreads();
    if (t < BM && b0 + t < n) {
        float s = 0.f;
#pragma unroll
        for (int c = 0; c < 32; ++c) s += red[t][c];
        float logit = s + b2[0];
        float attn  = 1.f / (1.f + expf(-logit));
        wout[elds[t]] = attn;
        ((int*)&rec[b0 + t])[3] = __float_as_int(attn);
    }
}

// ---------------------------------------------------------------------------
// Exact serial processing of one edge (deep-path fallback). Matches reference
// order: find(x)+compress, then find(y)+compress, then union.
// ---------------------------------------------------------------------------
__device__ __noinline__ void serial_edge2(int2* nd, const int* ri, int eidx) {
    int x = ri[eidx * 4 + 0], y = ri[eidx * 4 + 1];
    float w = __int_as_float(ri[eidx * 4 + 3]);
    int p, j;
    int rx = x;
    while ((p = nd[rx].x) != rx) rx = p;
    j = x;
    while ((p = nd[j].x) != rx) { nd[j].x = rx; j = p; }
    int ry = y;
    while ((p = nd[ry].x) != ry) ry = p;
    j = y;
    while ((p = nd[j].x) != ry) { nd[j].x = ry; j = p; }
    if (rx != ry) {
        float a = __int_as_float(nd[rx].y), b = __int_as_float(nd[ry].y);
        bool bx = a > b;
        int big = bx ? rx : ry, small = bx ? ry : rx;
        nd[small].x = big;
        nd[big].y = __float_as_int(bx ? (a + b * w) : (b + a * w));
    }
}

// ---------------------------------------------------------------------------
// Kernel 7: serial union-find in LDS with cross-edge software pipelining.
//   Level-0 records nd[x_i], nd[y_i] are pre-read TWO edges ahead (DS ops
//   execute in wave order -> a read issued before a write returns pre-write
//   data).  A pre-read is valid iff its node is not in the changed-write
//   sets of the two intervening edges (<=6 nodes each, register compares).
//   Stale (rare) -> fresh reread. Depth>3 -> exact serial fallback + poison.
// ---------------------------------------------------------------------------
__global__ __launch_bounds__(256) void uf_kernel(
        const int4* __restrict__ rec, const int* __restrict__ nmask,
        const int* __restrict__ orig, const float* __restrict__ rin,
        int* __restrict__ gpar, float* __restrict__ grank) {
    extern __shared__ char smem[];
    int2* nd = (int2*)smem;    // 128 KB {parent, rank-bits}
    int t = threadIdx.x;
    for (int c = t; c < NSLOTS; c += 256) {
        int o = orig[c];
        float r = (o >= 0) ? rin[o] : 1.0f;
        nd[c] = make_int2(c, __float_as_int(r));   // parent == arange
    }
    __syncthreads();

    if (t == 0) {
        const int n = *nmask;
        if (n > 0) {
            const int* ri = (const int*)rec;
            int4 e0 = rec[0], e1 = rec[1], e2 = rec[2];
            int2 ax0 = nd[e0.x], ay0 = nd[e0.y];   // pre-reads for edge 0
            int2 ax1 = nd[e1.x], ay1 = nd[e1.y];   // pre-reads for edge 1
            int wa0=-1,wa1=-1,wa2=-1,wa3=-1,wa4=-1,wa5=-1;  // W[i-1]
            int wb0=-1,wb1=-1,wb2=-1,wb3=-1,wb4=-1,wb5=-1;  // W[i-2]
            int poison = 0;

            for (int i = 0; i < n; ++i) {
                // pre-issue level-0 reads for edge i+2 (before this edge's
                // writes) and prefetch record i+3 (rec has 4 zero pads).
                int2 ax2 = nd[e2.x], ay2 = nd[e2.y];
                int4 enext = rec[i + 3];

                int x = e0.x, y = e0.y;
                float wi = __int_as_float(e0.w);

                bool stx = (poison > 0) | (x==wa0)|(x==wa1)|(x==wa2)|(x==wa3)|(x==wa4)|(x==wa5)
                                        | (x==wb0)|(x==wb1)|(x==wb2)|(x==wb3)|(x==wb4)|(x==wb5);
                bool sty = (poison > 0) | (y==wa0)|(y==wa1)|(y==wa2)|(y==wa3)|(y==wa4)|(y==wa5)
                                        | (y==wb0)|(y==wb1)|(y==wb2)|(y==wb3)|(y==wb4)|(y==wb5);
                int2 cx = ax0;
                int2 cy = ay0;
                if (__builtin_expect(stx, 0)) cx = nd[x];   // rare fresh reread
                if (__builtin_expect(sty, 0)) cy = nd[y];

                // ---- dual-chain find (level 0 free via pre-reads) ----
                bool fdx = (cx.x == x), fdy = (cy.x == y);
                int rootx = x, rooty = y;
                float rkx = __int_as_float(cx.y), rky = __int_as_float(cy.y);
                int v0x = x, v1x = -1, v0y = y, v1y = -1;  // first two path nodes
                int dx = 0, dy = 0;
                int curx = cx.x, cury = cy.x;
#pragma unroll
                for (int s = 0; s < 3; ++s) {
                    if (fdx && fdy) break;
                    int a1 = fdx ? rootx : curx;
                    int a2 = fdy ? rooty : cury;
                    int2 nx_ = nd[a1];
                    int2 ny_ = nd[a2];
                    if (!fdx) {
                        ++dx;
                        if (nx_.x == curx) { fdx = true; rootx = curx; rkx = __int_as_float(nx_.y); }
                        else { if (dx == 1) v1x = curx; curx = nx_.x; }
                    }
                    if (!fdy) {
                        ++dy;
                        if (ny_.x == cury) { fdy = true; rooty = cury; rky = __int_as_float(ny_.y); }
                        else { if (dy == 1) v1y = cury; cury = ny_.x; }
                    }
                }

                int px0=-1, px1=-1, py0=-1, py1=-1, smallN=-1, bigN=-1;
                if (fdx && fdy) {
                    // compression: changed writes only (value-preserving skipped)
                    if (dx >= 2) { nd[v0x].x = rootx; px0 = v0x; }
                    if (dx >= 3) { nd[v1x].x = rootx; px1 = v1x; }
                    if (dy >= 2) { nd[v0y].x = rooty; py0 = v0y; }
                    if (dy >= 3) { nd[v1y].x = rooty; py1 = v1y; }
                    if (rootx != rooty) {
                        bool bx = rkx > rky;
                        bigN   = bx ? rootx : rooty;
                        smallN = bx ? rooty : rootx;
                        nd[smallN].x = bigN;
                        float nr = bx ? (rkx + rky * wi) : (rky + rkx * wi);
                        nd[bigN].y = __float_as_int(nr);
                    }
                } else {
                    serial_edge2(nd, ri, i);   // exact fallback (deep path)
                    poison = 3;                // in-flight pre-reads suspect
                }

                // ---- shift pipeline state ----
                wb0=wa0; wb1=wa1; wb2=wa2; wb3=wa3; wb4=wa4; wb5=wa5;
                wa0=px0; wa1=px1; wa2=py0; wa3=py1; wa4=smallN; wa5=bigN;
                poison = (poison > 0) ? (poison - 1) : 0;
                ax0=ax1; ay0=ay1; ax1=ax2; ay1=ay2;
                e0=e1; e1=e2; e2=enext;
            }
        }
    }
    __syncthreads();
    for (int c = t; c < NSLOTS; c += 256) {
        int2 v = nd[c];
        gpar[c] = v.x;
        grank[c] = __int_as_float(v.y);
    }
}

// ---------------------------------------------------------------------------
// Kernel 8: finalize — per node, claimed -> compact result, else input copy.
// ---------------------------------------------------------------------------
__global__ void finalize_kernel(const int* __restrict__ pin, const float* __restrict__ rin,
                                const int* __restrict__ fo, const int* __restrict__ orig,
                                const int* __restrict__ gpar, const float* __restrict__ grank,
                                float* __restrict__ pout, float* __restrict__ rout) {
    int i = blockIdx.x * blockDim.x + threadIdx.x;
    if (i >= N_NODES) return;
    int c = fo[i];
    float pv, rv;
    if (c != 0x7FFFFFFF) {
        pv = (float)orig[gpar[c]];
        rv = grank[c];
    } else {
        pv = (float)pin[i];
        rv = rin[i];
    }
    pout[i] = pv;
    rout[i] = rv;
}

// ---------------------------------------------------------------------------
extern "C" void kernel_launch(void* const* d_in, const int* in_sizes, int n_in,
                              void* d_out, int out_size, void* d_ws, size_t ws_size,
                              hipStream_t stream) {
    const int*   x_idx = (const int*)d_in[0];
    const int*   y_idx = (const int*)d_in[1];
    const float* xf    = (const float*)d_in[2];
    const float* yf    = (const float*)d_in[3];
    const float* W1    = (const float*)d_in[4];
    const float* b1    = (const float*)d_in[5];
    const float* W2    = (const float*)d_in[6];
    const float* b2    = (const float*)d_in[7];
    const int*   pin   = (const int*)d_in[8];
    const float* rin   = (const float*)d_in[9];

    float* out   = (float*)d_out;
    float* w_out = out;                        // [E]
    float* pout  = out + E_EDGES;              // [N]
    float* rout  = out + E_EDGES + N_NODES;    // [N]

    char* ws = (char*)d_ws;
    float* sim_ws = (float*)(ws + 0);          //  32768 B
    int*   fo     = (int*)  (ws + 32768);      // 400000 B
    int*   orig   = (int*)  (ws + 432768);     //  65536 B
    int4*  rec    = (int4*) (ws + 498304);     // (E+4)*16 = 131136 B
    int*   nmask  = (int*)  (ws + 629440);     //     64 B
    int*   gpar   = (int*)  (ws + 629504);     //  65536 B
    float* grank  = (float*)(ws + 695040);     //  65536 B -> total 760576 B

    // 1) cosine sim
    sim_kernel<<<(E_EDGES * 64) / 256, 256, 0, stream>>>(xf, yf, sim_ws);
    // 2) compact-id mapping + zero w
    int g = (N_NODES + 255) / 256;
    initmap_kernel<<<g, 256, 0, stream>>>(fo, orig, w_out);
    claim_kernel<<<NSLOTS / 256, 256, 0, stream>>>(x_idx, y_idx, fo);
    orig_kernel<<<NSLOTS / 256, 256, 0, stream>>>(x_idx, y_idx, fo, orig);
    // 3) masked-edge compaction (records + padding)
    maskscan_kernel<<<1, 256, 0, stream>>>(x_idx, y_idx, fo, sim_ws, rec, nmask);
    // 4) gate MLP over masked edges only
    gate_kernel<<<E_EDGES / BM, 256, 0, stream>>>(xf, yf, W1, b1, W2, b2, rec, nmask, w_out);
    // 5) pipelined serial union-find in LDS (128 KB)
    uf_kernel<<<1, 256, 131072, stream>>>(rec, nmask, orig, rin, gpar, grank);
    // 6) finalize outputs (base copy + compact scatter fused)
    finalize_kernel<<<g, 256, 0, stream>>>(pin, rin, fo, orig, gpar, grank, pout, rout);
}

// Round 6
// 1908.122 us; speedup vs baseline: 1.3477x; 1.1246x over previous
//
#include <hip/hip_runtime.h>
#include <math.h>

#define E_EDGES 8192
#define D_FEAT 2048
#define K2 4096   // 2*D
#define H_DIM 128
#define N_NODES 100000
#define SIM_TH 0.7f
#define NSLOTS (2 * E_EDGES)   // 16384 compact slots

// ---------------------------------------------------------------------------
// Kernel 1: cosine similarity per edge. One wave (64 lanes) per edge.
// ---------------------------------------------------------------------------
__global__ __launch_bounds__(256) void sim_kernel(const float* __restrict__ xf,
                                                  const float* __restrict__ yf,
                                                  float* __restrict__ sim) {
    int gid  = blockIdx.x * blockDim.x + threadIdx.x;
    int wave = gid >> 6;
    int lane = threadIdx.x & 63;
    if (wave >= E_EDGES) return;
    const float4* xp = (const float4*)(xf + (size_t)wave * D_FEAT);
    const float4* yp = (const float4*)(yf + (size_t)wave * D_FEAT);
    float dot = 0.f, xx = 0.f, yy = 0.f;
#pragma unroll
    for (int j = 0; j < 8; ++j) {
        float4 a = xp[lane + j * 64];
        float4 b = yp[lane + j * 64];
        dot += a.x * b.x + a.y * b.y + a.z * b.z + a.w * b.w;
        xx  += a.x * a.x + a.y * a.y + a.z * a.z + a.w * a.w;
        yy  += b.x * b.x + b.y * b.y + b.z * b.z + b.w * b.w;
    }
#pragma unroll
    for (int off = 32; off; off >>= 1) {
        dot += __shfl_xor(dot, off);
        xx  += __shfl_xor(xx, off);
        yy  += __shfl_xor(yy, off);
    }
    if (lane == 0) {
        float nx = fmaxf(sqrtf(xx), 1e-8f);
        float ny = fmaxf(sqrtf(yy), 1e-8f);
        sim[wave] = dot / (nx * ny);
    }
}

// ---------------------------------------------------------------------------
// Kernel 2: init fo (=INT_MAX), orig (=-1), and zero w output.
// ---------------------------------------------------------------------------
__global__ void initmap_kernel(int* __restrict__ fo, int* __restrict__ orig,
                               float* __restrict__ wout) {
    int i = blockIdx.x * blockDim.x + threadIdx.x;
    if (i < N_NODES) fo[i] = 0x7FFFFFFF;
    if (i < NSLOTS)  orig[i] = -1;
    if (i < E_EDGES) wout[i] = 0.f;
}

// ---------------------------------------------------------------------------
// Kernel 3: claim compact slot = first occurrence index in x0,y0,x1,y1,...
// ---------------------------------------------------------------------------
__global__ void claim_kernel(const int* __restrict__ x_idx, const int* __restrict__ y_idx,
                             int* __restrict__ fo) {
    int i = blockIdx.x * blockDim.x + threadIdx.x;
    if (i >= NSLOTS) return;
    int e = i >> 1;
    int v = (i & 1) ? y_idx[e] : x_idx[e];
    atomicMin(&fo[v], i);
}

// ---------------------------------------------------------------------------
// Kernel 4: orig[slot] = node for claimed slots.
// ---------------------------------------------------------------------------
__global__ void orig_kernel(const int* __restrict__ x_idx, const int* __restrict__ y_idx,
                            const int* __restrict__ fo, int* __restrict__ orig) {
    int i = blockIdx.x * blockDim.x + threadIdx.x;
    if (i >= NSLOTS) return;
    int e = i >> 1;
    int v = (i & 1) ? y_idx[e] : x_idx[e];
    if (fo[v] == i) orig[i] = v;
}

// ---------------------------------------------------------------------------
// Kernel 5: order-preserving compaction of masked edges into records
//           rec = {cx, cy, eidx, (w filled later by gate)} + 4 zero pads.
// ---------------------------------------------------------------------------
__global__ __launch_bounds__(256) void maskscan_kernel(
        const int* __restrict__ x_idx, const int* __restrict__ y_idx,
        const int* __restrict__ fo, const float* __restrict__ sim,
        int4* __restrict__ rec, int* __restrict__ nmask) {
    __shared__ int partial[256];
    int t = threadIdx.x;
    int cnt = 0;
    for (int j = 0; j < 32; ++j) {
        int e = t * 32 + j;
        cnt += (sim[e] >= SIM_TH) ? 1 : 0;
    }
    partial[t] = cnt;
    __syncthreads();
    for (int off = 1; off < 256; off <<= 1) {
        int mine  = partial[t];
        int other = (t >= off) ? partial[t - off] : 0;
        __syncthreads();
        partial[t] = mine + other;
        __syncthreads();
    }
    int pos = partial[t] - cnt;
    if (t == 255) {
        int nn = partial[255];
        *nmask = nn;
        for (int j = 0; j < 4; ++j) rec[nn + j] = make_int4(0, 0, 0, 0);
    }
    for (int j = 0; j < 32; ++j) {
        int e = t * 32 + j;
        if (sim[e] >= SIM_TH) {
            int4 r;
            r.x = fo[x_idx[e]];
            r.y = fo[y_idx[e]];
            r.z = e;
            r.w = 0;
            rec[pos++] = r;
        }
    }
}

// ---------------------------------------------------------------------------
// Kernel 6: gate MLP over MASKED edges only (gathered rows).
// ---------------------------------------------------------------------------
#define BM 32
#define BK 32
#define SWZ(r, c) ((c) ^ ((((r) >> 2) & 7) << 2))

__global__ __launch_bounds__(256) void gate_kernel(
        const float* __restrict__ xf, const float* __restrict__ yf,
        const float* __restrict__ W1, const float* __restrict__ b1,
        const float* __restrict__ W2, const float* __restrict__ b2,
        int4* __restrict__ rec, const int* __restrict__ nmask,
        float* __restrict__ wout) {
    __shared__ float As[BM][BK];
    __shared__ float Bs[H_DIM][BK];
    __shared__ float red[BM][33];
    __shared__ int   elds[BM];

    int n  = *nmask;
    int b0 = blockIdx.x * BM;
    if (b0 >= n) return;

    int t  = threadIdx.x;
    if (t < BM) {
        int idx = b0 + t;
        elds[t] = (idx < n) ? rec[idx].z : rec[b0].z;
    }
    __syncthreads();

    int te = t >> 5;
    int tn = t & 31;
    int n0 = tn * 4;

    float acc[4][4] = {};

    for (int k0 = 0; k0 < K2; k0 += BK) {
        const float* src = (k0 < D_FEAT) ? xf : yf;
        int kk0 = (k0 < D_FEAT) ? k0 : (k0 - D_FEAT);
        {
            int row = t >> 3;
            int c   = (t & 7) * 4;
            float4 v = *(const float4*)(src + (size_t)elds[row] * D_FEAT + kk0 + c);
            *(float4*)(&As[row][SWZ(row, c)]) = v;
        }
#pragma unroll
        for (int r = 0; r < 4; ++r) {
            int nn = (t >> 3) + r * 32;
            int c  = (t & 7) * 4;
            float4 v = *(const float4*)(W1 + (size_t)nn * K2 + k0 + c);
            *(float4*)(&Bs[nn][SWZ(nn, c)]) = v;
        }
        __syncthreads();
        int swzA = (te & 7) << 2;
        int swzB = (tn & 7) << 2;
#pragma unroll
        for (int kk = 0; kk < BK; kk += 4) {
            float4 av[4], bv[4];
#pragma unroll
            for (int i = 0; i < 4; ++i)
                av[i] = *(const float4*)(&As[te * 4 + i][kk ^ swzA]);
#pragma unroll
            for (int j = 0; j < 4; ++j)
                bv[j] = *(const float4*)(&Bs[n0 + j][kk ^ swzB]);
#pragma unroll
            for (int i = 0; i < 4; ++i)
#pragma unroll
                for (int j = 0; j < 4; ++j)
                    acc[i][j] += av[i].x * bv[j].x + av[i].y * bv[j].y +
                                 av[i].z * bv[j].z + av[i].w * bv[j].w;
        }
        __syncthreads();
    }

    float b1v[4], w2v[4];
#pragma unroll
    for (int j = 0; j < 4; ++j) { b1v[j] = b1[n0 + j]; w2v[j] = W2[n0 + j]; }
#pragma unroll
    for (int i = 0; i < 4; ++i) {
        float p = 0.f;
#pragma unroll
        for (int j = 0; j < 4; ++j) {
            float h = fmaxf(acc[i][j] + b1v[j], 0.f);
            p += h * w2v[j];
        }
        red[te * 4 + i][tn] = p;
    }
    __syncthreads();
    if (t < BM && b0 + t < n) {
        float s = 0.f;
#pragma unroll
        for (int c = 0; c < 32; ++c) s += red[t][c];
        float logit = s + b2[0];
        float attn  = 1.f / (1.f + expf(-logit));
        wout[elds[t]] = attn;
        ((int*)&rec[b0 + t])[3] = __float_as_int(attn);
    }
}

// ---------------------------------------------------------------------------
// Exact serial processing of one edge (deep-path fallback). Matches reference
// order: find(x)+compress, then find(y)+compress, then union.
// ---------------------------------------------------------------------------
__device__ __noinline__ void serial_edge2(int2* nd, const int* ri, int eidx) {
    int x = ri[eidx * 4 + 0], y = ri[eidx * 4 + 1];
    float w = __int_as_float(ri[eidx * 4 + 3]);
    int p, j;
    int rx = x;
    while ((p = nd[rx].x) != rx) rx = p;
    j = x;
    while ((p = nd[j].x) != rx) { nd[j].x = rx; j = p; }
    int ry = y;
    while ((p = nd[ry].x) != ry) ry = p;
    j = y;
    while ((p = nd[j].x) != ry) { nd[j].x = ry; j = p; }
    if (rx != ry) {
        float a = __int_as_float(nd[rx].y), b = __int_as_float(nd[ry].y);
        bool bx = a > b;
        int big = bx ? rx : ry, small = bx ? ry : rx;
        nd[small].x = big;
        nd[big].y = __float_as_int(bx ? (a + b * w) : (b + a * w));
    }
}

// ---------------------------------------------------------------------------
// Kernel 7: serial union-find in LDS, 2-lane walker.
//   Lane 0 walks x's chain, lane 1 walks y's chain (one shared instruction
//   stream, one ds_read_b64 per level serves both).  {parent, rank} packed
//   int2.  Unrolled 2+2 levels with one mid ballot; depth>4 -> exact serial
//   fallback (walk is read-only).  Compression + union writes predicated
//   per-lane so both chains' writes share instructions.
// ---------------------------------------------------------------------------
__global__ __launch_bounds__(256) void uf_kernel(
        const int4* __restrict__ rec, const int* __restrict__ nmask,
        const int* __restrict__ orig, const float* __restrict__ rin,
        int* __restrict__ gpar, float* __restrict__ grank) {
    extern __shared__ char smem[];
    int2* nd = (int2*)smem;    // 128 KB {parent, rank-bits}
    int* ndw = (int*)smem;
    int t = threadIdx.x;
    for (int c = t; c < NSLOTS; c += 256) {
        int o = orig[c];
        float r = (o >= 0) ? rin[o] : 1.0f;
        nd[c] = make_int2(c, __float_as_int(r));   // parent == arange
    }
    __syncthreads();

    if (t < 64) {
        const int lane = t;
        const bool act = (lane < 2);
        const int* ri = (const int*)rec;
        const int n = *nmask;

        int4 e0 = rec[0];
        int4 e1 = rec[1];
        for (int i = 0; i < n; ++i) {
            int4 e2 = rec[i + 2];                    // prefetch (4 zero pads)
            int myS = act ? ((lane == 0) ? e0.x : e0.y) : 0;
            float wi = __int_as_float(e0.w);

            // ---- walk: levels 1-2, shared stream, both chains ----
            int cur = myS;
            bool done = !act;
            int root = cur; float rrk = 0.f;
            int q0 = 0, q1 = 0, q2 = 0;
            int d = 0;

            int2 pr = nd[cur];                        // level 1
            if (!done) {
                if (pr.x == cur) { root = cur; rrk = __int_as_float(pr.y); done = true; }
                else { q0 = cur; d = 1; cur = pr.x; }
            }
            pr = nd[cur];                             // level 2
            if (!done) {
                if (pr.x == cur) { root = cur; rrk = __int_as_float(pr.y); done = true; }
                else { q1 = cur; d = 2; cur = pr.x; }
            }
            bool deep = false;
            if (__ballot(!done) != 0ULL) {            // rare: depth > 2
                pr = nd[cur];                         // level 3
                if (!done) {
                    if (pr.x == cur) { root = cur; rrk = __int_as_float(pr.y); done = true; }
                    else { q2 = cur; d = 3; cur = pr.x; }
                }
                pr = nd[cur];                         // level 4
                if (!done) {
                    if (pr.x == cur) { root = cur; rrk = __int_as_float(pr.y); done = true; }
                    else { d = 4; }
                }
                deep = (__ballot(!done) != 0ULL);
            }

            if (__builtin_expect(deep, 0)) {
                if (lane == 0) serial_edge2(nd, ri, i);   // exact fallback
            } else {
                // ---- compression: changed writes only (last hop skipped) ----
                if (d >= 2) ndw[q0 * 2] = root;
                if (d >= 3) ndw[q1 * 2] = root;
                if (d >= 4) ndw[q2 * 2] = root;
                // ---- union: lanes 0,1 write {parent[small], rank[big]} ----
                int ro   = __shfl_xor(root, 1);
                float rko = __shfl_xor(rrk, 1);
                if (act && root != ro) {
                    int   rx = (lane == 0) ? root : ro;
                    int   ry = (lane == 0) ? ro : root;
                    float kx = (lane == 0) ? rrk : rko;
                    float ky = (lane == 0) ? rko : rrk;
                    bool bx  = kx > ky;
                    int big   = bx ? rx : ry;
                    int small = bx ? ry : rx;
                    float nr  = bx ? (kx + ky * wi) : (ky + kx * wi);
                    int waddr = (lane == 0) ? (small * 2) : (big * 2 + 1);
                    int wval  = (lane == 0) ? big : __float_as_int(nr);
                    ndw[waddr] = wval;
                }
            }
            e0 = e1; e1 = e2;
        }
    }
    __syncthreads();
    for (int c = t; c < NSLOTS; c += 256) {
        int2 v = nd[c];
        gpar[c] = v.x;
        grank[c] = __int_as_float(v.y);
    }
}

// ---------------------------------------------------------------------------
// Kernel 8: finalize — per node, claimed -> compact result, else input copy.
// ---------------------------------------------------------------------------
__global__ void finalize_kernel(const int* __restrict__ pin, const float* __restrict__ rin,
                                const int* __restrict__ fo, const int* __restrict__ orig,
                                const int* __restrict__ gpar, const float* __restrict__ grank,
                                float* __restrict__ pout, float* __restrict__ rout) {
    int i = blockIdx.x * blockDim.x + threadIdx.x;
    if (i >= N_NODES) return;
    int c = fo[i];
    float pv, rv;
    if (c != 0x7FFFFFFF) {
        pv = (float)orig[gpar[c]];
        rv = grank[c];
    } else {
        pv = (float)pin[i];
        rv = rin[i];
    }
    pout[i] = pv;
    rout[i] = rv;
}

// ---------------------------------------------------------------------------
extern "C" void kernel_launch(void* const* d_in, const int* in_sizes, int n_in,
                              void* d_out, int out_size, void* d_ws, size_t ws_size,
                              hipStream_t stream) {
    const int*   x_idx = (const int*)d_in[0];
    const int*   y_idx = (const int*)d_in[1];
    const float* xf    = (const float*)d_in[2];
    const float* yf    = (const float*)d_in[3];
    const float* W1    = (const float*)d_in[4];
    const float* b1    = (const float*)d_in[5];
    const float* W2    = (const float*)d_in[6];
    const float* b2    = (const float*)d_in[7];
    const int*   pin   = (const int*)d_in[8];
    const float* rin   = (const float*)d_in[9];

    float* out   = (float*)d_out;
    float* w_out = out;                        // [E]
    float* pout  = out + E_EDGES;              // [N]
    float* rout  = out + E_EDGES + N_NODES;    // [N]

    char* ws = (char*)d_ws;
    float* sim_ws = (float*)(ws + 0);          //  32768 B
    int*   fo     = (int*)  (ws + 32768);      // 400000 B
    int*   orig   = (int*)  (ws + 432768);     //  65536 B
    int4*  rec    = (int4*) (ws + 498304);     // (E+4)*16 = 131136 B
    int*   nmask  = (int*)  (ws + 629440);     //     64 B
    int*   gpar   = (int*)  (ws + 629504);     //  65536 B
    float* grank  = (float*)(ws + 695040);     //  65536 B -> total 760576 B

    // 1) cosine sim
    sim_kernel<<<(E_EDGES * 64) / 256, 256, 0, stream>>>(xf, yf, sim_ws);
    // 2) compact-id mapping + zero w
    int g = (N_NODES + 255) / 256;
    initmap_kernel<<<g, 256, 0, stream>>>(fo, orig, w_out);
    claim_kernel<<<NSLOTS / 256, 256, 0, stream>>>(x_idx, y_idx, fo);
    orig_kernel<<<NSLOTS / 256, 256, 0, stream>>>(x_idx, y_idx, fo, orig);
    // 3) masked-edge compaction (records + padding)
    maskscan_kernel<<<1, 256, 0, stream>>>(x_idx, y_idx, fo, sim_ws, rec, nmask);
    // 4) gate MLP over masked edges only
    gate_kernel<<<E_EDGES / BM, 256, 0, stream>>>(xf, yf, W1, b1, W2, b2, rec, nmask, w_out);
    // 5) 2-lane serial union-find in LDS (128 KB)
    uf_kernel<<<1, 256, 131072, stream>>>(rec, nmask, orig, rin, gpar, grank);
    // 6) finalize outputs (base copy + compact scatter fused)
    finalize_kernel<<<g, 256, 0, stream>>>(pin, rin, fo, orig, gpar, grank, pout, rout);
}

// Round 7
// 1228.129 us; speedup vs baseline: 2.0939x; 1.5537x over previous
//
#include <hip/hip_runtime.h>
#include <math.h>

#define E_EDGES 8192
#define D_FEAT 2048
#define K2 4096   // 2*D
#define H_DIM 128
#define N_NODES 100000
#define SIM_TH 0.7f
#define NSLOTS (2 * E_EDGES)   // 16384 compact slots

// ---------------------------------------------------------------------------
// Kernel 1: cosine similarity per edge. One wave (64 lanes) per edge.
// ---------------------------------------------------------------------------
__global__ __launch_bounds__(256) void sim_kernel(const float* __restrict__ xf,
                                                  const float* __restrict__ yf,
                                                  float* __restrict__ sim) {
    int gid  = blockIdx.x * blockDim.x + threadIdx.x;
    int wave = gid >> 6;
    int lane = threadIdx.x & 63;
    if (wave >= E_EDGES) return;
    const float4* xp = (const float4*)(xf + (size_t)wave * D_FEAT);
    const float4* yp = (const float4*)(yf + (size_t)wave * D_FEAT);
    float dot = 0.f, xx = 0.f, yy = 0.f;
#pragma unroll
    for (int j = 0; j < 8; ++j) {
        float4 a = xp[lane + j * 64];
        float4 b = yp[lane + j * 64];
        dot += a.x * b.x + a.y * b.y + a.z * b.z + a.w * b.w;
        xx  += a.x * a.x + a.y * a.y + a.z * a.z + a.w * a.w;
        yy  += b.x * b.x + b.y * b.y + b.z * b.z + b.w * b.w;
    }
#pragma unroll
    for (int off = 32; off; off >>= 1) {
        dot += __shfl_xor(dot, off);
        xx  += __shfl_xor(xx, off);
        yy  += __shfl_xor(yy, off);
    }
    if (lane == 0) {
        float nx = fmaxf(sqrtf(xx), 1e-8f);
        float ny = fmaxf(sqrtf(yy), 1e-8f);
        sim[wave] = dot / (nx * ny);
    }
}

// ---------------------------------------------------------------------------
// Kernel 2: init fo (=INT_MAX), orig (=-1), and zero w output.
// ---------------------------------------------------------------------------
__global__ void initmap_kernel(int* __restrict__ fo, int* __restrict__ orig,
                               float* __restrict__ wout) {
    int i = blockIdx.x * blockDim.x + threadIdx.x;
    if (i < N_NODES) fo[i] = 0x7FFFFFFF;
    if (i < NSLOTS)  orig[i] = -1;
    if (i < E_EDGES) wout[i] = 0.f;
}

// ---------------------------------------------------------------------------
// Kernel 3: claim compact slot = first occurrence index in x0,y0,x1,y1,...
// ---------------------------------------------------------------------------
__global__ void claim_kernel(const int* __restrict__ x_idx, const int* __restrict__ y_idx,
                             int* __restrict__ fo) {
    int i = blockIdx.x * blockDim.x + threadIdx.x;
    if (i >= NSLOTS) return;
    int e = i >> 1;
    int v = (i & 1) ? y_idx[e] : x_idx[e];
    atomicMin(&fo[v], i);
}

// ---------------------------------------------------------------------------
// Kernel 4: orig[slot] = node for claimed slots.
// ---------------------------------------------------------------------------
__global__ void orig_kernel(const int* __restrict__ x_idx, const int* __restrict__ y_idx,
                            const int* __restrict__ fo, int* __restrict__ orig) {
    int i = blockIdx.x * blockDim.x + threadIdx.x;
    if (i >= NSLOTS) return;
    int e = i >> 1;
    int v = (i & 1) ? y_idx[e] : x_idx[e];
    if (fo[v] == i) orig[i] = v;
}

// ---------------------------------------------------------------------------
// Kernel 5: order-preserving compaction of masked edges into records
//           rec = {cx, cy, eidx, (w filled later by gate)} + 4 zero pads.
// ---------------------------------------------------------------------------
__global__ __launch_bounds__(256) void maskscan_kernel(
        const int* __restrict__ x_idx, const int* __restrict__ y_idx,
        const int* __restrict__ fo, const float* __restrict__ sim,
        int4* __restrict__ rec, int* __restrict__ nmask) {
    __shared__ int partial[256];
    int t = threadIdx.x;
    int cnt = 0;
    for (int j = 0; j < 32; ++j) {
        int e = t * 32 + j;
        cnt += (sim[e] >= SIM_TH) ? 1 : 0;
    }
    partial[t] = cnt;
    __syncthreads();
    for (int off = 1; off < 256; off <<= 1) {
        int mine  = partial[t];
        int other = (t >= off) ? partial[t - off] : 0;
        __syncthreads();
        partial[t] = mine + other;
        __syncthreads();
    }
    int pos = partial[t] - cnt;
    if (t == 255) {
        int nn = partial[255];
        *nmask = nn;
        for (int j = 0; j < 4; ++j) rec[nn + j] = make_int4(0, 0, 0, 0);
    }
    for (int j = 0; j < 32; ++j) {
        int e = t * 32 + j;
        if (sim[e] >= SIM_TH) {
            int4 r;
            r.x = fo[x_idx[e]];
            r.y = fo[y_idx[e]];
            r.z = e;
            r.w = 0;
            rec[pos++] = r;
        }
    }
}

// ---------------------------------------------------------------------------
// Kernel 6: gate MLP over MASKED edges only (gathered rows).
// ---------------------------------------------------------------------------
#define BM 32
#define BK 32
#define SWZ(r, c) ((c) ^ ((((r) >> 2) & 7) << 2))

__global__ __launch_bounds__(256) void gate_kernel(
        const float* __restrict__ xf, const float* __restrict__ yf,
        const float* __restrict__ W1, const float* __restrict__ b1,
        const float* __restrict__ W2, const float* __restrict__ b2,
        int4* __restrict__ rec, const int* __restrict__ nmask,
        float* __restrict__ wout) {
    __shared__ float As[BM][BK];
    __shared__ float Bs[H_DIM][BK];
    __shared__ float red[BM][33];
    __shared__ int   elds[BM];

    int n  = *nmask;
    int b0 = blockIdx.x * BM;
    if (b0 >= n) return;

    int t  = threadIdx.x;
    if (t < BM) {
        int idx = b0 + t;
        elds[t] = (idx < n) ? rec[idx].z : rec[b0].z;
    }
    __syncthreads();

    int te = t >> 5;
    int tn = t & 31;
    int n0 = tn * 4;

    float acc[4][4] = {};

    for (int k0 = 0; k0 < K2; k0 += BK) {
        const float* src = (k0 < D_FEAT) ? xf : yf;
        int kk0 = (k0 < D_FEAT) ? k0 : (k0 - D_FEAT);
        {
            int row = t >> 3;
            int c   = (t & 7) * 4;
            float4 v = *(const float4*)(src + (size_t)elds[row] * D_FEAT + kk0 + c);
            *(float4*)(&As[row][SWZ(row, c)]) = v;
        }
#pragma unroll
        for (int r = 0; r < 4; ++r) {
            int nn = (t >> 3) + r * 32;
            int c  = (t & 7) * 4;
            float4 v = *(const float4*)(W1 + (size_t)nn * K2 + k0 + c);
            *(float4*)(&Bs[nn][SWZ(nn, c)]) = v;
        }
        __syncthreads();
        int swzA = (te & 7) << 2;
        int swzB = (tn & 7) << 2;
#pragma unroll
        for (int kk = 0; kk < BK; kk += 4) {
            float4 av[4], bv[4];
#pragma unroll
            for (int i = 0; i < 4; ++i)
                av[i] = *(const float4*)(&As[te * 4 + i][kk ^ swzA]);
#pragma unroll
            for (int j = 0; j < 4; ++j)
                bv[j] = *(const float4*)(&Bs[n0 + j][kk ^ swzB]);
#pragma unroll
            for (int i = 0; i < 4; ++i)
#pragma unroll
                for (int j = 0; j < 4; ++j)
                    acc[i][j] += av[i].x * bv[j].x + av[i].y * bv[j].y +
                                 av[i].z * bv[j].z + av[i].w * bv[j].w;
        }
        __syncthreads();
    }

    float b1v[4], w2v[4];
#pragma unroll
    for (int j = 0; j < 4; ++j) { b1v[j] = b1[n0 + j]; w2v[j] = W2[n0 + j]; }
#pragma unroll
    for (int i = 0; i < 4; ++i) {
        float p = 0.f;
#pragma unroll
        for (int j = 0; j < 4; ++j) {
            float h = fmaxf(acc[i][j] + b1v[j], 0.f);
            p += h * w2v[j];
        }
        red[te * 4 + i][tn] = p;
    }
    __syncthreads();
    if (t < BM && b0 + t < n) {
        float s = 0.f;
#pragma unroll
        for (int c = 0; c < 32; ++c) s += red[t][c];
        float logit = s + b2[0];
        float attn  = 1.f / (1.f + expf(-logit));
        wout[elds[t]] = attn;
        ((int*)&rec[b0 + t])[3] = __float_as_int(attn);
    }
}

// ---------------------------------------------------------------------------
// Exact serial processing of one edge (deep-path fallback). Matches reference
// order: find(x)+compress, then find(y)+compress, then union.
// ---------------------------------------------------------------------------
__device__ __noinline__ void serial_edge2(int2* nd, const int* ri, int eidx) {
    int x = ri[eidx * 4 + 0], y = ri[eidx * 4 + 1];
    float w = __int_as_float(ri[eidx * 4 + 3]);
    int p, j;
    int rx = x;
    while ((p = nd[rx].x) != rx) rx = p;
    j = x;
    while ((p = nd[j].x) != rx) { nd[j].x = rx; j = p; }
    int ry = y;
    while ((p = nd[ry].x) != ry) ry = p;
    j = y;
    while ((p = nd[j].x) != ry) { nd[j].x = ry; j = p; }
    if (rx != ry) {
        float a = __int_as_float(nd[rx].y), b = __int_as_float(nd[ry].y);
        bool bx = a > b;
        int big = bx ? rx : ry, small = bx ? ry : rx;
        nd[small].x = big;
        nd[big].y = __float_as_int(bx ? (a + b * w) : (b + a * w));
    }
}

// ---------------------------------------------------------------------------
// Kernel 7: serial union-find in LDS — single lane, packed int2 records,
//   register-held paths, unrolled walk (4 rounds) with early exit per round.
//   Hot case (both endpoints roots): 1 LDS round + union.  Depth>3 -> exact
//   serial fallback (walk is read-only until compression writes).
// ---------------------------------------------------------------------------
__global__ __launch_bounds__(256) void uf_kernel(
        const int4* __restrict__ rec, const int* __restrict__ nmask,
        const int* __restrict__ orig, const float* __restrict__ rin,
        int* __restrict__ gpar, float* __restrict__ grank) {
    extern __shared__ char smem[];
    int2* nd = (int2*)smem;    // 128 KB {parent, rank-bits}
    int* ndw = (int*)smem;
    int t = threadIdx.x;
    for (int c = t; c < NSLOTS; c += 256) {
        int o = orig[c];
        float r = (o >= 0) ? rin[o] : 1.0f;
        nd[c] = make_int2(c, __float_as_int(r));   // parent == arange
    }
    __syncthreads();

    if (t == 0) {
        const int n = *nmask;
        const int* ri = (const int*)rec;
        int4 e0 = rec[0];
        int4 e1 = rec[1];
        for (int i = 0; i < n; ++i) {
            int4 e2 = rec[i + 2];                 // prefetch (4 zero pads)
            int x = e0.x, y = e0.y;
            float wi = __int_as_float(e0.w);

            // ---- round 1: read both level-0 records (overlapped) ----
            int2 px = nd[x];
            int2 py = nd[y];
            bool fx = (px.x == x), fy = (py.x == y);
            int rx = x, ry = y;
            int kxb = px.y, kyb = py.y;           // rank bits at root
            bool ok = true;

            if (!(fx && fy)) {
                int cx1 = px.x, cy1 = py.x;       // distance-1 nodes
                bool wx0 = false, wx1f = false, wy0 = false, wy1f = false;
                // ---- round 2 ----
                int ax = fx ? rx : cx1, ay = fy ? ry : cy1;
                int2 qx = nd[ax];
                int2 qy = nd[ay];
                int cx2 = qx.x, cy2 = qy.x;
                if (!fx && qx.x == ax) { rx = ax; kxb = qx.y; fx = true; }   // d=1
                if (!fy && qy.x == ay) { ry = ay; kyb = qy.y; fy = true; }
                if (!(fx && fy)) {
                    // ---- round 3 ----
                    int bx_ = fx ? rx : cx2, by_ = fy ? ry : cy2;
                    int2 ux = nd[bx_];
                    int2 uy = nd[by_];
                    int cx3 = ux.x, cy3 = uy.x;
                    if (!fx && ux.x == bx_) { rx = bx_; kxb = ux.y; fx = true; wx0 = true; }   // d=2
                    if (!fy && uy.x == by_) { ry = by_; kyb = uy.y; fy = true; wy0 = true; }
                    if (!(fx && fy)) {
                        // ---- round 4 ----
                        int gx = fx ? rx : cx3, gy = fy ? ry : cy3;
                        int2 vx = nd[gx];
                        int2 vy = nd[gy];
                        if (!fx && vx.x == gx) { rx = gx; kxb = vx.y; fx = true; wx0 = true; wx1f = true; }  // d=3
                        if (!fy && vy.x == gy) { ry = gy; kyb = vy.y; fy = true; wy0 = true; wy1f = true; }
                        if (!(fx && fy)) { serial_edge2(nd, ri, i); ok = false; }   // deep
                    }
                }
                if (ok) {
                    // compression: changed writes only (value-preserving skipped)
                    if (wx0)  ndw[x * 2]   = rx;
                    if (wx1f) ndw[cx1 * 2] = rx;
                    if (wy0)  ndw[y * 2]   = ry;
                    if (wy1f) ndw[cy1 * 2] = ry;
                }
            }
            if (ok && rx != ry) {
                float kx = __int_as_float(kxb), ky = __int_as_float(kyb);
                bool bx = kx > ky;
                int big = bx ? rx : ry, small = bx ? ry : rx;
                float nr = bx ? (kx + ky * wi) : (ky + kx * wi);
                ndw[small * 2]   = big;
                ndw[big * 2 + 1] = __float_as_int(nr);
            }
            e0 = e1; e1 = e2;
        }
    }
    __syncthreads();
    for (int c = t; c < NSLOTS; c += 256) {
        int2 v = nd[c];
        gpar[c] = v.x;
        grank[c] = __int_as_float(v.y);
    }
}

// ---------------------------------------------------------------------------
// Kernel 8: finalize — per node, claimed -> compact result, else input copy.
// ---------------------------------------------------------------------------
__global__ void finalize_kernel(const int* __restrict__ pin, const float* __restrict__ rin,
                                const int* __restrict__ fo, const int* __restrict__ orig,
                                const int* __restrict__ gpar, const float* __restrict__ grank,
                                float* __restrict__ pout, float* __restrict__ rout) {
    int i = blockIdx.x * blockDim.x + threadIdx.x;
    if (i >= N_NODES) return;
    int c = fo[i];
    float pv, rv;
    if (c != 0x7FFFFFFF) {
        pv = (float)orig[gpar[c]];
        rv = grank[c];
    } else {
        pv = (float)pin[i];
        rv = rin[i];
    }
    pout[i] = pv;
    rout[i] = rv;
}

// ---------------------------------------------------------------------------
extern "C" void kernel_launch(void* const* d_in, const int* in_sizes, int n_in,
                              void* d_out, int out_size, void* d_ws, size_t ws_size,
                              hipStream_t stream) {
    const int*   x_idx = (const int*)d_in[0];
    const int*   y_idx = (const int*)d_in[1];
    const float* xf    = (const float*)d_in[2];
    const float* yf    = (const float*)d_in[3];
    const float* W1    = (const float*)d_in[4];
    const float* b1    = (const float*)d_in[5];
    const float* W2    = (const float*)d_in[6];
    const float* b2    = (const float*)d_in[7];
    const int*   pin   = (const int*)d_in[8];
    const float* rin   = (const float*)d_in[9];

    float* out   = (float*)d_out;
    float* w_out = out;                        // [E]
    float* pout  = out + E_EDGES;              // [N]
    float* rout  = out + E_EDGES + N_NODES;    // [N]

    char* ws = (char*)d_ws;
    float* sim_ws = (float*)(ws + 0);          //  32768 B
    int*   fo     = (int*)  (ws + 32768);      // 400000 B
    int*   orig   = (int*)  (ws + 432768);     //  65536 B
    int4*  rec    = (int4*) (ws + 498304);     // (E+4)*16 = 131136 B
    int*   nmask  = (int*)  (ws + 629440);     //     64 B
    int*   gpar   = (int*)  (ws + 629504);     //  65536 B
    float* grank  = (float*)(ws + 695040);     //  65536 B -> total 760576 B

    // 1) cosine sim
    sim_kernel<<<(E_EDGES * 64) / 256, 256, 0, stream>>>(xf, yf, sim_ws);
    // 2) compact-id mapping + zero w
    int g = (N_NODES + 255) / 256;
    initmap_kernel<<<g, 256, 0, stream>>>(fo, orig, w_out);
    claim_kernel<<<NSLOTS / 256, 256, 0, stream>>>(x_idx, y_idx, fo);
    orig_kernel<<<NSLOTS / 256, 256, 0, stream>>>(x_idx, y_idx, fo, orig);
    // 3) masked-edge compaction (records + padding)
    maskscan_kernel<<<1, 256, 0, stream>>>(x_idx, y_idx, fo, sim_ws, rec, nmask);
    // 4) gate MLP over masked edges only
    gate_kernel<<<E_EDGES / BM, 256, 0, stream>>>(xf, yf, W1, b1, W2, b2, rec, nmask, w_out);
    // 5) single-lane packed union-find in LDS (128 KB)
    uf_kernel<<<1, 256, 131072, stream>>>(rec, nmask, orig, rin, gpar, grank);
    // 6) finalize outputs (base copy + compact scatter fused)
    finalize_kernel<<<g, 256, 0, stream>>>(pin, rin, fo, orig, gpar, grank, pout, rout);
}